// Round 17
// baseline (466.502 us; speedup 1.0000x reference)
//
#include <hip/hip_runtime.h>
#include <hip/hip_bf16.h>
#include <math.h>

#define WB 4
#define WS 2048
#define WD 512
#define WHID 64
#define NLAYER 6

typedef __attribute__((ext_vector_type(8))) short short8;
typedef __attribute__((ext_vector_type(4))) short short4v;
typedef __attribute__((ext_vector_type(4))) float floatx4;
typedef __attribute__((ext_vector_type(16))) float floatx16;

__device__ __forceinline__ short f2bf(float f) {
    union { float f; unsigned u; } x; x.f = f;
    unsigned r = (x.u + 0x7fffu + ((x.u >> 16) & 1u)) >> 16;
    return (short)r;
}

__device__ __forceinline__ float bf2f(short s) {
    union { unsigned u; float f; } c;
    c.u = ((unsigned)(unsigned short)s) << 16;
    return c.f;
}

__device__ __forceinline__ void gl_lds16(const short* g, short* l) {
    __builtin_amdgcn_global_load_lds(
        (const __attribute__((address_space(1))) unsigned*)g,
        (__attribute__((address_space(3))) unsigned*)l, 16, 0, 0);
}

// bijective XCD-aware block swizzle (nwg % 8 == 0)
__device__ __forceinline__ void xcd_swz(int& bx, int& by, int& bz) {
    int gx = gridDim.x, gy = gridDim.y;
    int nwg = gx * gy * gridDim.z;
    int wg = blockIdx.x + gx * (blockIdx.y + gy * blockIdx.z);
    int swz = (wg & 7) * (nwg >> 3) + (wg >> 3);
    bx = swz % gx;
    int t = swz / gx;
    by = t % gy;
    bz = t / gy;
}

// ---------- fused QK'+softmax-exp+PV: 128x128 tile, 32x32x16 MFMA ----------
// 64 KB staging LDS -> 2 blocks/CU; P tile (32 KB) reuses As after K-loop.
__global__ __launch_bounds__(512) void qkpv_k(
    const short* __restrict__ A, const short* __restrict__ Bm,
    const short* __restrict__ Vw, short* __restrict__ Pp,
    float* __restrict__ Lp, const float* __restrict__ rq)
{
    __shared__ __align__(16) short As[2][128 * 64];
    __shared__ __align__(16) short Bs[2][128 * 64];
    int bx, by, bz;
    xcd_swz(bx, by, bz);
    int tid = threadIdx.x;
    int m0 = by * 128, n0 = bx * 128;
    const short* Ab = A + (long)bz * WS * WD + (long)m0 * WD;
    const short* Bb = Bm + (long)bz * WS * WD + (long)n0 * WD;

    int lane = tid & 63, w = tid >> 6;
    int l31 = lane & 31, lh = lane >> 5;
    int wm = (w >> 2) * 64, wn = (w & 3) * 32;

    floatx16 acc[2];
#pragma unroll
    for (int mi = 0; mi < 2; mi++)
#pragma unroll
        for (int r = 0; r < 16; r++) acc[mi][r] = 0.f;

    int sr = tid >> 3;                      // 0..63
    int scb = (tid & 7) ^ (sr & 7);
    const short* ga0 = Ab + (long)sr * WD + scb * 8;
    const short* gb0 = Bb + (long)sr * WD + scb * 8;
    long ld64 = (long)64 * WD;

    int aob[2], ax[2];
#pragma unroll
    for (int i = 0; i < 2; i++) {
        int ar = wm + i * 32 + l31;
        aob[i] = ar * 64; ax[i] = ar & 7;
    }
    int br = wn + l31;
    int bob = br * 64, bxx = br & 7;

    auto stage = [&](int t, int b) {
        const short* ga = ga0 + t * 64;
        const short* gb = gb0 + t * 64;
#pragma unroll
        for (int q = 0; q < 2; q++)
            gl_lds16(ga + (long)q * ld64, &As[b][q * 4096 + tid * 8]);
#pragma unroll
        for (int q = 0; q < 2; q++)
            gl_lds16(gb + (long)q * ld64, &Bs[b][q * 4096 + tid * 8]);
    };

    stage(0, 0);

    const int nt = WD >> 6;
    for (int t = 0; t < nt; t++) {
        int cur = t & 1;
        if (t + 1 < nt) {
            stage(t + 1, cur ^ 1);
            asm volatile("s_waitcnt vmcnt(4)" ::: "memory");
        } else {
            asm volatile("s_waitcnt vmcnt(0)" ::: "memory");
        }
        __builtin_amdgcn_s_barrier();
        __builtin_amdgcn_sched_barrier(0);
        const short* as = As[cur];
        const short* bs = Bs[cur];
#pragma unroll
        for (int kk = 0; kk < 4; kk++) {
            short8 av[2], bv;
#pragma unroll
            for (int i = 0; i < 2; i++)
                av[i] = *(const short8*)&as[aob[i] + (((2 * kk + lh) ^ ax[i]) * 8)];
            bv = *(const short8*)&bs[bob + (((2 * kk + lh) ^ bxx) * 8)];
#pragma unroll
            for (int mi = 0; mi < 2; mi++)
                acc[mi] = __builtin_amdgcn_mfma_f32_32x32x16_bf16(av[mi], bv, acc[mi], 0, 0, 0);
        }
        __builtin_amdgcn_sched_barrier(0);
        __builtin_amdgcn_s_barrier();
    }

    // exp -> P into LDS [128][128] (XOR-swizzled 16B blocks) + row-sum partials
    short* Pl = (short*)As;                 // 32 KB
    float rv = rq[(long)bz * WS + n0 + wn + l31];
    int cb3 = (wn + l31) >> 3, cb7 = l31 & 7;
#pragma unroll
    for (int mi = 0; mi < 2; mi++) {
        float s[16];
#pragma unroll
        for (int r = 0; r < 16; r++) {
            int row = wm + mi * 32 + 4 * lh + (r & 3) + 8 * (r >> 2);
            float e = __expf(acc[mi][r] + rv);
            int blk = cb3 ^ (row & 7);
            Pl[row * 128 + blk * 8 + cb7] = f2bf(e);
            s[r] = e;
        }
#pragma unroll
        for (int off = 1; off < 32; off <<= 1)
#pragma unroll
            for (int r = 0; r < 16; r++) s[r] += __shfl_xor(s[r], off);
        if (l31 == 0) {
            long lpb = ((long)bz * 64 + bx * 4 + (w & 3)) * WS + m0 + wm + mi * 32 + 4 * lh;
#pragma unroll
            for (int r = 0; r < 16; r++)
                Lp[lpb + (r & 3) + 8 * (r >> 2)] = s[r];
        }
    }
    __syncthreads();

    // PV: wave w computes rows w*16..+15 x 64 j, K=128 from LDS P; V from global (L2)
    {
        int m0w = w * 16;
        int l15 = lane & 15, kb = lane >> 4;
        floatx4 acc2[4];
#pragma unroll
        for (int ni = 0; ni < 4; ni++) acc2[ni] = (floatx4){0.f, 0.f, 0.f, 0.f};
        const short* vb = Vw + (long)bz * WHID * WS + n0;
        int row = m0w + l15;
#pragma unroll
        for (int ks = 0; ks < 4; ks++) {
            int kc = ks * 32 + kb * 8;
            int blk = (kc >> 3) ^ (row & 7);
            short8 av2 = *(const short8*)&Pl[row * 128 + blk * 8];
            short8 bv2[4];
#pragma unroll
            for (int ni = 0; ni < 4; ni++) {
                int j = ni * 16 + l15;
                bv2[ni] = *(const short8*)&vb[(long)j * WS + kc];
            }
#pragma unroll
            for (int ni = 0; ni < 4; ni++)
                acc2[ni] = __builtin_amdgcn_mfma_f32_16x16x32_bf16(av2, bv2[ni], acc2[ni], 0, 0, 0);
        }
        int rl = kb * 4;
        short* pp = Pp + (((long)bx * WB + bz) * WS + m0 + m0w) * WHID;
#pragma unroll
        for (int ni = 0; ni < 4; ni++) {
            int j = ni * 16 + l15;
#pragma unroll
            for (int q = 0; q < 4; q++)
                pp[(long)(rl + q) * WHID + j] = f2bf(acc2[ni][q]);
        }
    }
}

// ---------- fused tail: Pp-reduce(16) + relu + FFN2 + residual + LN1 + LN2 ----------
__global__ __launch_bounds__(512) void tail_k(
    const short* __restrict__ Pp, const float* __restrict__ Lp,
    const float* __restrict__ b1, const short* __restrict__ w2t,
    const float* __restrict__ b2,
    const float* __restrict__ g1, const float* __restrict__ bb1,
    const float* __restrict__ g2, const float* __restrict__ bb2,
    short* __restrict__ hbf, float* __restrict__ outp, float sc)
{
    __shared__ __align__(16) short hids[32 * 64];
    __shared__ float ffs[32 * 521];
    int tid = threadIdx.x;
    int lane = tid & 63, w = tid >> 6;
    int row0 = blockIdx.x * 32;

    // step 1: hid = relu(sc/l * sum_bxp Pp + b1) -> hids (bf16, swizzled)
    {
        int r = tid >> 4, l16 = tid & 15;
        int m = row0 + r;
        int b = m >> 11, mm = m & (WS - 1);
        const float* lp = Lp + (long)b * 64 * WS + mm;
        float lv = 0.f;
#pragma unroll
        for (int i = 0; i < 4; i++) lv += lp[(long)(l16 * 4 + i) * WS];
#pragma unroll
        for (int off = 1; off < 16; off <<= 1) lv += __shfl_xor(lv, off);
        float scl = sc / lv;
        int j0 = l16 * 4;
        float4 s4 = make_float4(0.f, 0.f, 0.f, 0.f);
#pragma unroll
        for (int bxp = 0; bxp < 16; bxp++) {
            short4v v = *(const short4v*)&Pp[(((long)bxp * WB + b) * WS + mm) * WHID + j0];
            s4.x += bf2f(v[0]); s4.y += bf2f(v[1]); s4.z += bf2f(v[2]); s4.w += bf2f(v[3]);
        }
        short4v hv;
        hv[0] = f2bf(fmaxf(s4.x * scl + b1[j0], 0.f));
        hv[1] = f2bf(fmaxf(s4.y * scl + b1[j0 + 1], 0.f));
        hv[2] = f2bf(fmaxf(s4.z * scl + b1[j0 + 2], 0.f));
        hv[3] = f2bf(fmaxf(s4.w * scl + b1[j0 + 3], 0.f));
        *(short4v*)&hids[r * 64 + (((j0 >> 3) ^ (r & 7)) * 8) + (j0 & 7)] = hv;
    }
    __syncthreads();

    // step 2: ff = hid @ W2 : 8 waves 2Mx4N, wave 16x128, K=64; W2 frags from global
    {
        int wm = (w >> 2) * 16, wn = (w & 3) * 128;
        int l15 = lane & 15, kb = lane >> 4;
        floatx4 acc[8];
#pragma unroll
        for (int ni = 0; ni < 8; ni++) acc[ni] = (floatx4){0.f, 0.f, 0.f, 0.f};
#pragma unroll
        for (int st = 0; st < 2; st++) {
            int jb = st * 4 + kb;
            int ar = wm + l15;
            short8 a = *(const short8*)&hids[ar * 64 + ((jb ^ (ar & 7)) * 8)];
#pragma unroll
            for (int ni = 0; ni < 8; ni++) {
                int n = wn + ni * 16 + l15;
                short8 bf = *(const short8*)&w2t[n * 64 + jb * 8];
                acc[ni] = __builtin_amdgcn_mfma_f32_16x16x32_bf16(a, bf, acc[ni], 0, 0, 0);
            }
        }
#pragma unroll
        for (int ni = 0; ni < 8; ni++) {
            int n = wn + ni * 16 + l15;
            float bvv = b2[n];
#pragma unroll
            for (int q = 0; q < 4; q++) {
                int rr = wm + kb * 4 + q;
                ffs[rr * 521 + n] = acc[ni][q] + bvv;
            }
        }
    }
    __syncthreads();

    // LN1+LN2 per row; wave handles rows w*4..+3
    for (int rr = w * 4; rr < w * 4 + 4; rr++) {
        long m2 = row0 + rr;
        float v[8];
        float s = 0.f;
#pragma unroll
        for (int cc = 0; cc < 8; cc++) {
            int col = lane + 64 * cc;
            float fv = ffs[rr * 521 + col];
            float hv2 = bf2f(hbf[m2 * WD + col]);
            v[cc] = fv + hv2;
            s += v[cc];
        }
#pragma unroll
        for (int off = 1; off < 64; off <<= 1) s += __shfl_xor(s, off);
        float mu = s * (1.f / WD);
        float var = 0.f;
#pragma unroll
        for (int cc = 0; cc < 8; cc++) { v[cc] -= mu; var += v[cc] * v[cc]; }
#pragma unroll
        for (int off = 1; off < 64; off <<= 1) var += __shfl_xor(var, off);
        float rs = rsqrtf(var * (1.f / WD) + 1e-5f);
        float s2 = 0.f;
#pragma unroll
        for (int cc = 0; cc < 8; cc++) {
            int col = lane + 64 * cc;
            v[cc] = v[cc] * rs * g1[col] + bb1[col];
            s2 += v[cc];
        }
#pragma unroll
        for (int off = 1; off < 64; off <<= 1) s2 += __shfl_xor(s2, off);
        float mu2 = s2 * (1.f / WD);
        float var2 = 0.f;
#pragma unroll
        for (int cc = 0; cc < 8; cc++) { v[cc] -= mu2; var2 += v[cc] * v[cc]; }
#pragma unroll
        for (int off = 1; off < 64; off <<= 1) var2 += __shfl_xor(var2, off);
        float rs2 = rsqrtf(var2 * (1.f / WD) + 1e-5f);
#pragma unroll
        for (int cc = 0; cc < 8; cc++) {
            int col = lane + 64 * cc;
            float z = v[cc] * rs2 * g2[col] + bb2[col];
            hbf[m2 * WD + col] = f2bf(z);
            if (outp) outp[m2 * WD + col] = z;
        }
    }
}

// ---------- 128x128 NT GEMM, 8 waves, BK=64, 2-buf counted-vmcnt ----------
template<int EPI>
__global__ __launch_bounds__(512) void gemm8_k(
    const short* __restrict__ A, const short* __restrict__ Bm,
    const float* __restrict__ bias, short* __restrict__ Cb,
    int K, int lda, int ldb, int ldc,
    long sA, long sB, long sC, float scale, int b0)
{
    __shared__ __align__(16) short As[2][128 * 64];
    __shared__ __align__(16) short Bs[2][128 * 64];
    int bx, by, bz0;
    xcd_swz(bx, by, bz0);
    int tid = threadIdx.x;
    int bz = b0 + bz0;
    int m0 = by * 128, n0 = bx * 128;
    const short* Ab = A + (long)bz * sA + (long)m0 * lda;
    const short* Bb = Bm + (long)bz * sB + (long)n0 * ldb;
    long coff = (long)bz * sC;

    int lane = tid & 63, w = tid >> 6;
    int wm = (w >> 2) * 64, wn = (w & 3) * 32;

    floatx4 acc[4][2];
#pragma unroll
    for (int mi = 0; mi < 4; mi++)
#pragma unroll
        for (int ni = 0; ni < 2; ni++) acc[mi][ni] = (floatx4){0.f, 0.f, 0.f, 0.f};

    int r0 = tid >> 3;
    int sblk = (tid & 7) ^ (r0 & 7);
    const short* ga0 = Ab + (long)r0 * lda + sblk * 8;
    const short* gb0 = Bb + (long)r0 * ldb + sblk * 8;
    long lda64 = (long)64 * lda, ldb64 = (long)64 * ldb;

    int arow = wm + (lane & 15);
    int brow = wn + (lane & 15);
    int a7 = arow & 7, b7 = brow & 7;
    int kb = lane >> 4;
    int aoff0 = arow * 64 + ((kb ^ a7) * 8);
    int aoff1 = arow * 64 + (((kb + 4) ^ a7) * 8);
    int boff0 = brow * 64 + ((kb ^ b7) * 8);
    int boff1 = brow * 64 + (((kb + 4) ^ b7) * 8);

    int nt = K >> 6;

    auto stage = [&](int t, int b) {
        const short* ga = ga0 + t * 64;
        const short* gb = gb0 + t * 64;
        gl_lds16(ga, &As[b][tid * 8]);
        gl_lds16(ga + lda64, &As[b][(tid + 512) * 8]);
        gl_lds16(gb, &Bs[b][tid * 8]);
        gl_lds16(gb + ldb64, &Bs[b][(tid + 512) * 8]);
    };

    stage(0, 0);

    for (int t = 0; t < nt; t++) {
        int cur = t & 1;
        if (t + 1 < nt) {
            stage(t + 1, cur ^ 1);
            asm volatile("s_waitcnt vmcnt(4)" ::: "memory");
        } else {
            asm volatile("s_waitcnt vmcnt(0)" ::: "memory");
        }
        __builtin_amdgcn_s_barrier();
        __builtin_amdgcn_sched_barrier(0);
        const short* as = As[cur];
        const short* bs = Bs[cur];
        short8 av[4], bv[2];
#pragma unroll
        for (int i = 0; i < 4; i++) av[i] = *(const short8*)&as[aoff0 + i * 16 * 64];
#pragma unroll
        for (int i = 0; i < 2; i++) bv[i] = *(const short8*)&bs[boff0 + i * 16 * 64];
#pragma unroll
        for (int mi = 0; mi < 4; mi++)
#pragma unroll
            for (int ni = 0; ni < 2; ni++)
                acc[mi][ni] = __builtin_amdgcn_mfma_f32_16x16x32_bf16(av[mi], bv[ni], acc[mi][ni], 0, 0, 0);
#pragma unroll
        for (int i = 0; i < 4; i++) av[i] = *(const short8*)&as[aoff1 + i * 16 * 64];
#pragma unroll
        for (int i = 0; i < 2; i++) bv[i] = *(const short8*)&bs[boff1 + i * 16 * 64];
#pragma unroll
        for (int mi = 0; mi < 4; mi++)
#pragma unroll
            for (int ni = 0; ni < 2; ni++)
                acc[mi][ni] = __builtin_amdgcn_mfma_f32_16x16x32_bf16(av[mi], bv[ni], acc[mi][ni], 0, 0, 0);
        __builtin_amdgcn_sched_barrier(0);
        __builtin_amdgcn_s_barrier();
    }

    int rl = (lane >> 4) * 4, col = lane & 15;

#pragma unroll
    for (int mi = 0; mi < 4; mi++) {
#pragma unroll
        for (int ni = 0; ni < 2; ni++) {
            int n = n0 + wn + ni * 16 + col;
            if (EPI == 8) {
                int m = m0 + wm + mi * 16 + rl;
                short4v o;
#pragma unroll
                for (int j = 0; j < 4; j++) o[j] = f2bf(acc[mi][ni][j] * scale);
                *(short4v*)&Cb[coff + (long)n * ldc + m] = o;
            } else {
                float bvv = bias ? bias[n] : 0.f;
#pragma unroll
                for (int j = 0; j < 4; j++) {
                    int r = wm + mi * 16 + rl + j;
                    float v = (acc[mi][ni][j] + bvv) * scale;
                    Cb[coff + (long)(m0 + r) * ldc + n] = f2bf(v);
                }
            }
        }
    }
}

// rq[b][n] = sc_attn * dot(bq, k[b][n])
__global__ __launch_bounds__(256) void rq_k(const short* __restrict__ kbf,
                                            const float* __restrict__ bq,
                                            float* __restrict__ rq)
{
    __shared__ float sbq[WD];
    int tid = threadIdx.x;
    for (int i = tid; i < WD; i += 256) sbq[i] = bq[i];
    __syncthreads();
    int idx = blockIdx.x * 256 + tid;
    const short* kr = kbf + (long)idx * WD;
    float s = 0.f;
    for (int d = 0; d < WD; d += 8) {
        short8 kv = *(const short8*)(kr + d);
#pragma unroll
        for (int e = 0; e < 8; e++) s += bf2f(kv[e]) * sbq[d + e];
    }
    rq[idx] = s * 0.125f;
}

// ---------------- 64-tile GEMM (M<=64): C = A@B^T * scale, bf16 out ----------------
__global__ __launch_bounds__(256) void gemm_k(
    const short* __restrict__ A, const short* __restrict__ Bm,
    short* __restrict__ Cb,
    int M, int N, int K, int lda, int ldb, int ldc,
    long sA, long sB, long sC, float scale, int b0)
{
    __shared__ short As[64][40];
    __shared__ short Bs[64][40];
    int bx, by, bz0;
    xcd_swz(bx, by, bz0);
    int tid = threadIdx.x;
    int bz = b0 + bz0;
    const short* Ab = A + (long)bz * sA;
    const short* Bb = Bm + (long)bz * sB;
    long coff = (long)bz * sC;
    int m0 = by * 64, n0 = bx * 64;

    floatx4 acc[4];
#pragma unroll
    for (int c = 0; c < 4; c++) acc[c] = (floatx4){0.f, 0.f, 0.f, 0.f};

    int lane = tid & 63, w = tid >> 6;
    int arow = w * 16 + (lane & 15);
    int koff = (lane >> 4) * 8;

    for (int kt = 0; kt < K; kt += 32) {
        {
            int r = tid >> 2, kc = (tid & 3) * 8;
            int ar = m0 + r < M ? m0 + r : M - 1;
            short8 av = *(const short8*)(Ab + (long)ar * lda + kt + kc);
            *(short8*)&As[r][kc] = av;
        }
        {
            int r = tid >> 2, kc = (tid & 3) * 8;
            short8 bv = *(const short8*)(Bb + (long)(n0 + r) * ldb + kt + kc);
            *(short8*)&Bs[r][kc] = bv;
        }
        __syncthreads();
        short8 a = *(const short8*)&As[arow][koff];
#pragma unroll
        for (int c = 0; c < 4; c++) {
            short8 b = *(const short8*)&Bs[c * 16 + (lane & 15)][koff];
            acc[c] = __builtin_amdgcn_mfma_f32_16x16x32_bf16(a, b, acc[c], 0, 0, 0);
        }
        __syncthreads();
    }

    int rl = (lane >> 4) * 4, col = lane & 15;
    int mb = m0 + w * 16 + rl;
#pragma unroll
    for (int c = 0; c < 4; c++) {
        int n = n0 + c * 16 + col;
#pragma unroll
        for (int j = 0; j < 4; j++) {
            int m = mb + j;
            if (m < M) Cb[coff + (long)m * ldc + n] = f2bf(acc[c][j] * scale);
        }
    }
}

__global__ void conv_x_k(const float* __restrict__ x, short* __restrict__ hbf, int n4)
{
    int i = blockIdx.x * blockDim.x + threadIdx.x;
    for (; i < n4; i += gridDim.x * blockDim.x) {
        float4 v = ((const float4*)x)[i];
        short4v o;
        o[0] = f2bf(v.x); o[1] = f2bf(v.y); o[2] = f2bf(v.z); o[3] = f2bf(v.w);
        *(short4v*)&hbf[i * 4] = o;
    }
}

__global__ void conv_w_k(const float* __restrict__ x, short* __restrict__ w, int n4)
{
    int i = blockIdx.x * blockDim.x + threadIdx.x;
    for (; i < n4; i += gridDim.x * blockDim.x) {
        float4 v = ((const float4*)x)[i];
        short4v o;
        o[0] = f2bf(v.x); o[1] = f2bf(v.y); o[2] = f2bf(v.z); o[3] = f2bf(v.w);
        *(short4v*)&w[i * 4] = o;
    }
}

// W [R][C] f32 -> Wt [C][R] bf16
__global__ __launch_bounds__(256) void transpose_w_k(const float* __restrict__ W,
                                                     short* __restrict__ Wt, int R, int C)
{
    __shared__ short t[32][33];
    int c0 = blockIdx.x * 32, r0 = blockIdx.y * 32;
    int tx = threadIdx.x & 31, ty = threadIdx.x >> 5;
#pragma unroll
    for (int i = 0; i < 32; i += 8)
        t[ty + i][tx] = f2bf(W[(long)(r0 + ty + i) * C + c0 + tx]);
    __syncthreads();
#pragma unroll
    for (int i = 0; i < 32; i += 8)
        Wt[(long)(c0 + ty + i) * R + r0 + tx] = t[tx][ty + i];
}

extern "C" void kernel_launch(void* const* d_in, const int* in_sizes, int n_in,
                              void* d_out, int out_size, void* d_ws, size_t ws_size,
                              hipStream_t stream)
{
    const float* x   = (const float*)d_in[0];
    const float* Wq  = (const float*)d_in[1];
    const float* bq  = (const float*)d_in[2];
    const float* Wk  = (const float*)d_in[3];
    const float* bk  = (const float*)d_in[4];
    const float* Wv  = (const float*)d_in[5];
    const float* bv  = (const float*)d_in[6];
    const float* W1  = (const float*)d_in[7];
    const float* b1  = (const float*)d_in[8];
    const float* W2  = (const float*)d_in[9];
    const float* b2  = (const float*)d_in[10];
    const float* g1  = (const float*)d_in[11];
    const float* lb1 = (const float*)d_in[12];
    const float* g2  = (const float*)d_in[13];
    const float* lb2 = (const float*)d_in[14];
    float* out = (float*)d_out;

    char* p = (char*)d_ws;
    auto carve = [&](size_t bytes) -> char* {
        char* r = p;
        p += (bytes + 255) & ~(size_t)255;
        return r;
    };
    short* hbf  = (short*)carve((size_t)WB * WS * WD * 2);
    short* kbf  = (short*)carve((size_t)WB * WS * WD * 2);
    short* vbf  = (short*)carve((size_t)WB * WS * WD * 2);
    short* Gt   = (short*)carve((size_t)WB * WS * WD * 2);   // [b][n][e]
    short* vw1t = (short*)carve((size_t)WB * WHID * WS * 2); // [b][j][s]
    short* wqb  = (short*)carve((size_t)WD * WD * 2);
    short* wkt  = (short*)carve((size_t)WD * WD * 2);
    short* wvt  = (short*)carve((size_t)WD * WD * 2);
    short* w1t  = (short*)carve((size_t)WHID * WD * 2);      // [64][512]
    short* w2t  = (short*)carve((size_t)WD * WHID * 2);      // [512][64]
    float* rq   = (float*)carve((size_t)WB * WS * 4);
    float* Lp   = (float*)carve((size_t)WB * 64 * WS * 4);
    short* Pp   = (short*)carve((size_t)16 * WB * WS * WHID * 2);

    const int M = WB * WS;
    const float sc_attn = 0.125f;
    const float sc_out  = 0.04419417382f;   // 1/sqrt(512)

    conv_x_k<<<2048, 256, 0, stream>>>(x, hbf, WB * WS * WD / 4);
    conv_w_k<<<256, 256, 0, stream>>>(Wq, wqb, WD * WD / 4);
    transpose_w_k<<<dim3(WD / 32, WD / 32), 256, 0, stream>>>(Wk, wkt, WD, WD);
    transpose_w_k<<<dim3(WD / 32, WD / 32), 256, 0, stream>>>(Wv, wvt, WD, WD);
    transpose_w_k<<<dim3(WHID / 32, WD / 32), 256, 0, stream>>>(W1, w1t, WD, WHID);
    transpose_w_k<<<dim3(WD / 32, WHID / 32), 256, 0, stream>>>(W2, w2t, WHID, WD);

    // k = x @ Wk + bk ; v = x @ Wv + bv
    gemm8_k<0><<<dim3(WD / 128, M / 128, 1), 512, 0, stream>>>(
        hbf, wkt, bk, kbf, WD, WD, WD, WD, 0, 0, 0, 1.0f, 0);
    gemm8_k<0><<<dim3(WD / 128, M / 128, 1), 512, 0, stream>>>(
        hbf, wvt, bv, vbf, WD, WD, WD, WD, 0, 0, 0, 1.0f, 0);

    // Gt[b][n][e] = sc_attn * sum_d Wq[e][d]*k[b][n][d]
    gemm8_k<8><<<dim3(WS / 128, WD / 128, WB), 512, 0, stream>>>(
        wqb, kbf, nullptr, Gt, WD, WD, WD, WD,
        0, (long)WS * WD, (long)WS * WD, sc_attn, 0);
    // rq[b][n] = sc_attn * dot(bq, k[b][n])
    rq_k<<<WB * WS / 256, 256, 0, stream>>>(kbf, bq, rq);
    // vw1t[b][j][s] = sum_d W1[d][j]*v[b][s][d]
    gemm_k<<<dim3(WS / 64, 1, WB), 256, 0, stream>>>(
        w1t, vbf, vw1t, WHID, WS, WD, WD, WD, WS,
        0, (long)WS * WD, (long)WHID * WS, 1.0f, 0);

    for (int l = 0; l < NLAYER; l++) {
        qkpv_k<<<dim3(WS / 128, WS / 128, WB), 512, 0, stream>>>(
            hbf, Gt, vw1t, Pp, Lp, rq);
        tail_k<<<M / 32, 512, 0, stream>>>(
            Pp, Lp, b1, w2t, b2, g1, lb1, g2, lb2, hbf,
            (l == NLAYER - 1) ? out : nullptr, sc_out);
    }
}

// Round 18
// 333.547 us; speedup vs baseline: 1.3986x; 1.3986x over previous
//
#include <hip/hip_runtime.h>
#include <hip/hip_bf16.h>
#include <math.h>

#define WB 4
#define WS 2048
#define WD 512
#define WHID 64
#define NLAYER 6

typedef __attribute__((ext_vector_type(8))) short short8;
typedef __attribute__((ext_vector_type(4))) short short4v;
typedef __attribute__((ext_vector_type(4))) float floatx4;
typedef __attribute__((ext_vector_type(16))) float floatx16;

__device__ __forceinline__ short f2bf(float f) {
    union { float f; unsigned u; } x; x.f = f;
    unsigned r = (x.u + 0x7fffu + ((x.u >> 16) & 1u)) >> 16;
    return (short)r;
}

__device__ __forceinline__ float bf2f(short s) {
    union { unsigned u; float f; } c;
    c.u = ((unsigned)(unsigned short)s) << 16;
    return c.f;
}

__device__ __forceinline__ void gl_lds16(const short* g, short* l) {
    __builtin_amdgcn_global_load_lds(
        (const __attribute__((address_space(1))) unsigned*)g,
        (__attribute__((address_space(3))) unsigned*)l, 16, 0, 0);
}

// bijective XCD-aware block swizzle (nwg % 8 == 0)
__device__ __forceinline__ void xcd_swz(int& bx, int& by, int& bz) {
    int gx = gridDim.x, gy = gridDim.y;
    int nwg = gx * gy * gridDim.z;
    int wg = blockIdx.x + gx * (blockIdx.y + gy * blockIdx.z);
    int swz = (wg & 7) * (nwg >> 3) + (wg >> 3);
    bx = swz % gx;
    int t = swz / gx;
    by = t % gy;
    bz = t / gy;
}

// ---------- fused QK'+softmax-exp+PV: 256x256 tile, 32x32x16 MFMA ----------
// Lp row-sums computed in PV phase via ones-column MFMA (8 partials/row).
__global__ __launch_bounds__(512) void qkpv_k(
    const short* __restrict__ A, const short* __restrict__ Bm,
    const short* __restrict__ Vw, short* __restrict__ Pp,
    float* __restrict__ Lp, const float* __restrict__ rq)
{
    __shared__ __align__(16) short As[2][256 * 64];
    __shared__ __align__(16) short Bs[2][256 * 64];
    int bx, by, bz;
    xcd_swz(bx, by, bz);
    int tid = threadIdx.x;
    int m0 = by * 256, n0 = bx * 256;
    const short* Ab = A + (long)bz * WS * WD + (long)m0 * WD;
    const short* Bb = Bm + (long)bz * WS * WD + (long)n0 * WD;

    int lane = tid & 63, w = tid >> 6;
    int l31 = lane & 31, lh = lane >> 5;
    int wm = (w >> 2) * 128, wn = (w & 3) * 64;

    floatx16 acc[4][2];
#pragma unroll
    for (int mi = 0; mi < 4; mi++)
#pragma unroll
        for (int ni = 0; ni < 2; ni++)
#pragma unroll
            for (int r = 0; r < 16; r++) acc[mi][ni][r] = 0.f;

    int sr = tid >> 3;
    int scb = (tid & 7) ^ (sr & 7);
    const short* ga0 = Ab + (long)sr * WD + scb * 8;
    const short* gb0 = Bb + (long)sr * WD + scb * 8;
    long ld64 = (long)64 * WD;

    int aob[4], ax[4], bob[2], bx_[2];
#pragma unroll
    for (int i = 0; i < 4; i++) {
        int ar = wm + i * 32 + l31;
        aob[i] = ar * 64; ax[i] = ar & 7;
    }
#pragma unroll
    for (int i = 0; i < 2; i++) {
        int br = wn + i * 32 + l31;
        bob[i] = br * 64; bx_[i] = br & 7;
    }

    auto stage = [&](int t, int b) {
        const short* ga = ga0 + t * 64;
        const short* gb = gb0 + t * 64;
#pragma unroll
        for (int q = 0; q < 4; q++)
            gl_lds16(ga + (long)q * ld64, &As[b][q * 4096 + tid * 8]);
#pragma unroll
        for (int q = 0; q < 4; q++)
            gl_lds16(gb + (long)q * ld64, &Bs[b][q * 4096 + tid * 8]);
    };

    stage(0, 0);

    const int nt = WD >> 6;
    for (int t = 0; t < nt; t++) {
        int cur = t & 1;
        if (t + 1 < nt) {
            stage(t + 1, cur ^ 1);
            asm volatile("s_waitcnt vmcnt(8)" ::: "memory");
        } else {
            asm volatile("s_waitcnt vmcnt(0)" ::: "memory");
        }
        __builtin_amdgcn_s_barrier();
        __builtin_amdgcn_sched_barrier(0);
        const short* as = As[cur];
        const short* bs = Bs[cur];
#pragma unroll
        for (int kk = 0; kk < 4; kk++) {
            short8 av[4], bv[2];
#pragma unroll
            for (int i = 0; i < 4; i++)
                av[i] = *(const short8*)&as[aob[i] + (((2 * kk + lh) ^ ax[i]) * 8)];
#pragma unroll
            for (int i = 0; i < 2; i++)
                bv[i] = *(const short8*)&bs[bob[i] + (((2 * kk + lh) ^ bx_[i]) * 8)];
#pragma unroll
            for (int mi = 0; mi < 4; mi++)
#pragma unroll
                for (int ni = 0; ni < 2; ni++)
                    acc[mi][ni] = __builtin_amdgcn_mfma_f32_32x32x16_bf16(av[mi], bv[ni], acc[mi][ni], 0, 0, 0);
        }
        __builtin_amdgcn_sched_barrier(0);
        __builtin_amdgcn_s_barrier();
    }

    // exp -> P into LDS (swizzled halves); no in-epilogue row sums
    short* Pl = (short*)As;
    short* Ph = (short*)Bs;
    float rv0 = rq[(long)bz * WS + n0 + wn + l31];
    float rv1 = rq[(long)bz * WS + n0 + wn + 32 + l31];
#pragma unroll
    for (int mi = 0; mi < 4; mi++) {
#pragma unroll
        for (int ni = 0; ni < 2; ni++) {
            int c = wn + ni * 32 + l31;
            short* Pt = (c < 128) ? Pl : Ph;
            int cc = c & 127;
            float rv = ni ? rv1 : rv0;
#pragma unroll
            for (int r = 0; r < 16; r++) {
                int row = wm + mi * 32 + 4 * lh + (r & 3) + 8 * (r >> 2);
                float e = __expf(acc[mi][ni][r] + rv);
                int blk = (cc >> 3) ^ (row & 7);
                Pt[row * 128 + blk * 8 + (cc & 7)] = f2bf(e);
            }
        }
    }
    __syncthreads();

    // PV: wave w computes rows w*32..+31 x 64 j, K=256 from LDS P; ones-col -> Lp
    {
        int m0w = w * 32;
        int l15 = lane & 15, kb = lane >> 4;
        floatx4 acc2[2][4];
        floatx4 accl[2];
#pragma unroll
        for (int mi = 0; mi < 2; mi++) {
#pragma unroll
            for (int ni = 0; ni < 4; ni++) acc2[mi][ni] = (floatx4){0.f, 0.f, 0.f, 0.f};
            accl[mi] = (floatx4){0.f, 0.f, 0.f, 0.f};
        }
        short8 ones8;
#pragma unroll
        for (int e = 0; e < 8; e++) ones8[e] = (short)0x3F80;  // bf16 1.0
        const short* vb = Vw + (long)bz * WHID * WS + n0;
#pragma unroll
        for (int ks = 0; ks < 8; ks++) {
            int kc = ks * 32 + kb * 8;
            const short* Pt = (kc < 128) ? Pl : Ph;
            int cc = kc & 127;
            short8 av2[2], bv2[4];
#pragma unroll
            for (int mi = 0; mi < 2; mi++) {
                int row = m0w + mi * 16 + l15;
                int blk = (cc >> 3) ^ (row & 7);
                av2[mi] = *(const short8*)&Pt[row * 128 + blk * 8];
            }
#pragma unroll
            for (int ni = 0; ni < 4; ni++) {
                int j = ni * 16 + l15;
                bv2[ni] = *(const short8*)&vb[(long)j * WS + kc];
            }
#pragma unroll
            for (int mi = 0; mi < 2; mi++) {
#pragma unroll
                for (int ni = 0; ni < 4; ni++)
                    acc2[mi][ni] = __builtin_amdgcn_mfma_f32_16x16x32_bf16(av2[mi], bv2[ni], acc2[mi][ni], 0, 0, 0);
                accl[mi] = __builtin_amdgcn_mfma_f32_16x16x32_bf16(av2[mi], ones8, accl[mi], 0, 0, 0);
            }
        }
        int rl = kb * 4;
        short* pp = Pp + (((long)bx * WB + bz) * WS + m0 + m0w) * WHID;
#pragma unroll
        for (int mi = 0; mi < 2; mi++)
#pragma unroll
            for (int ni = 0; ni < 4; ni++) {
                int j = ni * 16 + l15;
#pragma unroll
                for (int q = 0; q < 4; q++)
                    pp[(long)(mi * 16 + rl + q) * WHID + j] = f2bf(acc2[mi][ni][q]);
            }
        if (l15 == 0) {
            float* lp = Lp + ((long)bz * 8 + bx) * WS + m0 + m0w;
#pragma unroll
            for (int mi = 0; mi < 2; mi++)
#pragma unroll
                for (int q = 0; q < 4; q++)
                    lp[mi * 16 + rl + q] = accl[mi][q];
        }
    }
}

// ---------- fused tail: Pp-reduce(8) + relu + FFN2 + residual + LN1 + LN2 ----------
__global__ __launch_bounds__(512) void tail_k(
    const short* __restrict__ Pp, const float* __restrict__ Lp,
    const float* __restrict__ b1, const short* __restrict__ w2t,
    const float* __restrict__ b2,
    const float* __restrict__ g1, const float* __restrict__ bb1,
    const float* __restrict__ g2, const float* __restrict__ bb2,
    short* __restrict__ hbf, float* __restrict__ outp, float sc)
{
    __shared__ __align__(16) short hids[32 * 64];
    __shared__ float ffs[32 * 521];
    int tid = threadIdx.x;
    int lane = tid & 63, w = tid >> 6;
    int row0 = blockIdx.x * 32;

    // step 1: hid = relu(sc/l * sum_bxp Pp + b1) -> hids (bf16, swizzled)
    {
        int r = tid >> 4, l16 = tid & 15;
        int m = row0 + r;
        int b = m >> 11, mm = m & (WS - 1);
        const float* lp = Lp + (long)b * 8 * WS + mm;
        float lv = 0.f;
#pragma unroll
        for (int p2 = 0; p2 < 8; p2++) lv += lp[(long)p2 * WS];
        float scl = sc / lv;
        int j0 = l16 * 4;
        float4 s4 = make_float4(0.f, 0.f, 0.f, 0.f);
#pragma unroll
        for (int bxp = 0; bxp < 8; bxp++) {
            short4v v = *(const short4v*)&Pp[(((long)bxp * WB + b) * WS + mm) * WHID + j0];
            s4.x += bf2f(v[0]); s4.y += bf2f(v[1]); s4.z += bf2f(v[2]); s4.w += bf2f(v[3]);
        }
        short4v hv;
        hv[0] = f2bf(fmaxf(s4.x * scl + b1[j0], 0.f));
        hv[1] = f2bf(fmaxf(s4.y * scl + b1[j0 + 1], 0.f));
        hv[2] = f2bf(fmaxf(s4.z * scl + b1[j0 + 2], 0.f));
        hv[3] = f2bf(fmaxf(s4.w * scl + b1[j0 + 3], 0.f));
        *(short4v*)&hids[r * 64 + (((j0 >> 3) ^ (r & 7)) * 8) + (j0 & 7)] = hv;
    }
    __syncthreads();

    // step 2: ff = hid @ W2 : 8 waves 2Mx4N, wave 16x128, K=64; W2 frags from global
    {
        int wm = (w >> 2) * 16, wn = (w & 3) * 128;
        int l15 = lane & 15, kb = lane >> 4;
        floatx4 acc[8];
#pragma unroll
        for (int ni = 0; ni < 8; ni++) acc[ni] = (floatx4){0.f, 0.f, 0.f, 0.f};
#pragma unroll
        for (int st = 0; st < 2; st++) {
            int jb = st * 4 + kb;
            int ar = wm + l15;
            short8 a = *(const short8*)&hids[ar * 64 + ((jb ^ (ar & 7)) * 8)];
#pragma unroll
            for (int ni = 0; ni < 8; ni++) {
                int n = wn + ni * 16 + l15;
                short8 bf = *(const short8*)&w2t[n * 64 + jb * 8];
                acc[ni] = __builtin_amdgcn_mfma_f32_16x16x32_bf16(a, bf, acc[ni], 0, 0, 0);
            }
        }
#pragma unroll
        for (int ni = 0; ni < 8; ni++) {
            int n = wn + ni * 16 + l15;
            float bvv = b2[n];
#pragma unroll
            for (int q = 0; q < 4; q++) {
                int rr = wm + kb * 4 + q;
                ffs[rr * 521 + n] = acc[ni][q] + bvv;
            }
        }
    }
    __syncthreads();

    // LN1+LN2 per row; wave handles rows w*4..+3
    for (int rr = w * 4; rr < w * 4 + 4; rr++) {
        long m2 = row0 + rr;
        float v[8];
        float s = 0.f;
#pragma unroll
        for (int cc = 0; cc < 8; cc++) {
            int col = lane + 64 * cc;
            float fv = ffs[rr * 521 + col];
            float hv2 = bf2f(hbf[m2 * WD + col]);
            v[cc] = fv + hv2;
            s += v[cc];
        }
#pragma unroll
        for (int off = 1; off < 64; off <<= 1) s += __shfl_xor(s, off);
        float mu = s * (1.f / WD);
        float var = 0.f;
#pragma unroll
        for (int cc = 0; cc < 8; cc++) { v[cc] -= mu; var += v[cc] * v[cc]; }
#pragma unroll
        for (int off = 1; off < 64; off <<= 1) var += __shfl_xor(var, off);
        float rs = rsqrtf(var * (1.f / WD) + 1e-5f);
        float s2 = 0.f;
#pragma unroll
        for (int cc = 0; cc < 8; cc++) {
            int col = lane + 64 * cc;
            v[cc] = v[cc] * rs * g1[col] + bb1[col];
            s2 += v[cc];
        }
#pragma unroll
        for (int off = 1; off < 64; off <<= 1) s2 += __shfl_xor(s2, off);
        float mu2 = s2 * (1.f / WD);
        float var2 = 0.f;
#pragma unroll
        for (int cc = 0; cc < 8; cc++) { v[cc] -= mu2; var2 += v[cc] * v[cc]; }
#pragma unroll
        for (int off = 1; off < 64; off <<= 1) var2 += __shfl_xor(var2, off);
        float rs2 = rsqrtf(var2 * (1.f / WD) + 1e-5f);
#pragma unroll
        for (int cc = 0; cc < 8; cc++) {
            int col = lane + 64 * cc;
            float z = v[cc] * rs2 * g2[col] + bb2[col];
            hbf[m2 * WD + col] = f2bf(z);
            if (outp) outp[m2 * WD + col] = z;
        }
    }
}

// ---------- 128x128 NT GEMM, 8 waves, BK=64, 2-buf counted-vmcnt ----------
template<int EPI>
__global__ __launch_bounds__(512) void gemm8_k(
    const short* __restrict__ A, const short* __restrict__ Bm,
    const float* __restrict__ bias, short* __restrict__ Cb,
    int K, int lda, int ldb, int ldc,
    long sA, long sB, long sC, float scale, int b0)
{
    __shared__ __align__(16) short As[2][128 * 64];
    __shared__ __align__(16) short Bs[2][128 * 64];
    int bx, by, bz0;
    xcd_swz(bx, by, bz0);
    int tid = threadIdx.x;
    int bz = b0 + bz0;
    int m0 = by * 128, n0 = bx * 128;
    const short* Ab = A + (long)bz * sA + (long)m0 * lda;
    const short* Bb = Bm + (long)bz * sB + (long)n0 * ldb;
    long coff = (long)bz * sC;

    int lane = tid & 63, w = tid >> 6;
    int wm = (w >> 2) * 64, wn = (w & 3) * 32;

    floatx4 acc[4][2];
#pragma unroll
    for (int mi = 0; mi < 4; mi++)
#pragma unroll
        for (int ni = 0; ni < 2; ni++) acc[mi][ni] = (floatx4){0.f, 0.f, 0.f, 0.f};

    int r0 = tid >> 3;
    int sblk = (tid & 7) ^ (r0 & 7);
    const short* ga0 = Ab + (long)r0 * lda + sblk * 8;
    const short* gb0 = Bb + (long)r0 * ldb + sblk * 8;
    long lda64 = (long)64 * lda, ldb64 = (long)64 * ldb;

    int arow = wm + (lane & 15);
    int brow = wn + (lane & 15);
    int a7 = arow & 7, b7 = brow & 7;
    int kb = lane >> 4;
    int aoff0 = arow * 64 + ((kb ^ a7) * 8);
    int aoff1 = arow * 64 + (((kb + 4) ^ a7) * 8);
    int boff0 = brow * 64 + ((kb ^ b7) * 8);
    int boff1 = brow * 64 + (((kb + 4) ^ b7) * 8);

    int nt = K >> 6;

    auto stage = [&](int t, int b) {
        const short* ga = ga0 + t * 64;
        const short* gb = gb0 + t * 64;
        gl_lds16(ga, &As[b][tid * 8]);
        gl_lds16(ga + lda64, &As[b][(tid + 512) * 8]);
        gl_lds16(gb, &Bs[b][tid * 8]);
        gl_lds16(gb + ldb64, &Bs[b][(tid + 512) * 8]);
    };

    stage(0, 0);

    for (int t = 0; t < nt; t++) {
        int cur = t & 1;
        if (t + 1 < nt) {
            stage(t + 1, cur ^ 1);
            asm volatile("s_waitcnt vmcnt(4)" ::: "memory");
        } else {
            asm volatile("s_waitcnt vmcnt(0)" ::: "memory");
        }
        __builtin_amdgcn_s_barrier();
        __builtin_amdgcn_sched_barrier(0);
        const short* as = As[cur];
        const short* bs = Bs[cur];
        short8 av[4], bv[2];
#pragma unroll
        for (int i = 0; i < 4; i++) av[i] = *(const short8*)&as[aoff0 + i * 16 * 64];
#pragma unroll
        for (int i = 0; i < 2; i++) bv[i] = *(const short8*)&bs[boff0 + i * 16 * 64];
#pragma unroll
        for (int mi = 0; mi < 4; mi++)
#pragma unroll
            for (int ni = 0; ni < 2; ni++)
                acc[mi][ni] = __builtin_amdgcn_mfma_f32_16x16x32_bf16(av[mi], bv[ni], acc[mi][ni], 0, 0, 0);
#pragma unroll
        for (int i = 0; i < 4; i++) av[i] = *(const short8*)&as[aoff1 + i * 16 * 64];
#pragma unroll
        for (int i = 0; i < 2; i++) bv[i] = *(const short8*)&bs[boff1 + i * 16 * 64];
#pragma unroll
        for (int mi = 0; mi < 4; mi++)
#pragma unroll
            for (int ni = 0; ni < 2; ni++)
                acc[mi][ni] = __builtin_amdgcn_mfma_f32_16x16x32_bf16(av[mi], bv[ni], acc[mi][ni], 0, 0, 0);
        __builtin_amdgcn_sched_barrier(0);
        __builtin_amdgcn_s_barrier();
    }

    int rl = (lane >> 4) * 4, col = lane & 15;

#pragma unroll
    for (int mi = 0; mi < 4; mi++) {
#pragma unroll
        for (int ni = 0; ni < 2; ni++) {
            int n = n0 + wn + ni * 16 + col;
            if (EPI == 8) {
                int m = m0 + wm + mi * 16 + rl;
                short4v o;
#pragma unroll
                for (int j = 0; j < 4; j++) o[j] = f2bf(acc[mi][ni][j] * scale);
                *(short4v*)&Cb[coff + (long)n * ldc + m] = o;
            } else {
                float bvv = bias ? bias[n] : 0.f;
#pragma unroll
                for (int j = 0; j < 4; j++) {
                    int r = wm + mi * 16 + rl + j;
                    float v = (acc[mi][ni][j] + bvv) * scale;
                    Cb[coff + (long)(m0 + r) * ldc + n] = f2bf(v);
                }
            }
        }
    }
}

// rq[b][n] = sc_attn * dot(bq, k[b][n])
__global__ __launch_bounds__(256) void rq_k(const short* __restrict__ kbf,
                                            const float* __restrict__ bq,
                                            float* __restrict__ rq)
{
    __shared__ float sbq[WD];
    int tid = threadIdx.x;
    for (int i = tid; i < WD; i += 256) sbq[i] = bq[i];
    __syncthreads();
    int idx = blockIdx.x * 256 + tid;
    const short* kr = kbf + (long)idx * WD;
    float s = 0.f;
    for (int d = 0; d < WD; d += 8) {
        short8 kv = *(const short8*)(kr + d);
#pragma unroll
        for (int e = 0; e < 8; e++) s += bf2f(kv[e]) * sbq[d + e];
    }
    rq[idx] = s * 0.125f;
}

// ---------------- 64-tile GEMM (M<=64): C = A@B^T * scale, bf16 out ----------------
__global__ __launch_bounds__(256) void gemm_k(
    const short* __restrict__ A, const short* __restrict__ Bm,
    short* __restrict__ Cb,
    int M, int N, int K, int lda, int ldb, int ldc,
    long sA, long sB, long sC, float scale, int b0)
{
    __shared__ short As[64][40];
    __shared__ short Bs[64][40];
    int bx, by, bz0;
    xcd_swz(bx, by, bz0);
    int tid = threadIdx.x;
    int bz = b0 + bz0;
    const short* Ab = A + (long)bz * sA;
    const short* Bb = Bm + (long)bz * sB;
    long coff = (long)bz * sC;
    int m0 = by * 64, n0 = bx * 64;

    floatx4 acc[4];
#pragma unroll
    for (int c = 0; c < 4; c++) acc[c] = (floatx4){0.f, 0.f, 0.f, 0.f};

    int lane = tid & 63, w = tid >> 6;
    int arow = w * 16 + (lane & 15);
    int koff = (lane >> 4) * 8;

    for (int kt = 0; kt < K; kt += 32) {
        {
            int r = tid >> 2, kc = (tid & 3) * 8;
            int ar = m0 + r < M ? m0 + r : M - 1;
            short8 av = *(const short8*)(Ab + (long)ar * lda + kt + kc);
            *(short8*)&As[r][kc] = av;
        }
        {
            int r = tid >> 2, kc = (tid & 3) * 8;
            short8 bv = *(const short8*)(Bb + (long)(n0 + r) * ldb + kt + kc);
            *(short8*)&Bs[r][kc] = bv;
        }
        __syncthreads();
        short8 a = *(const short8*)&As[arow][koff];
#pragma unroll
        for (int c = 0; c < 4; c++) {
            short8 b = *(const short8*)&Bs[c * 16 + (lane & 15)][koff];
            acc[c] = __builtin_amdgcn_mfma_f32_16x16x32_bf16(a, b, acc[c], 0, 0, 0);
        }
        __syncthreads();
    }

    int rl = (lane >> 4) * 4, col = lane & 15;
    int mb = m0 + w * 16 + rl;
#pragma unroll
    for (int c = 0; c < 4; c++) {
        int n = n0 + c * 16 + col;
#pragma unroll
        for (int j = 0; j < 4; j++) {
            int m = mb + j;
            if (m < M) Cb[coff + (long)m * ldc + n] = f2bf(acc[c][j] * scale);
        }
    }
}

__global__ void conv_x_k(const float* __restrict__ x, short* __restrict__ hbf, int n4)
{
    int i = blockIdx.x * blockDim.x + threadIdx.x;
    for (; i < n4; i += gridDim.x * blockDim.x) {
        float4 v = ((const float4*)x)[i];
        short4v o;
        o[0] = f2bf(v.x); o[1] = f2bf(v.y); o[2] = f2bf(v.z); o[3] = f2bf(v.w);
        *(short4v*)&hbf[i * 4] = o;
    }
}

__global__ void conv_w_k(const float* __restrict__ x, short* __restrict__ w, int n4)
{
    int i = blockIdx.x * blockDim.x + threadIdx.x;
    for (; i < n4; i += gridDim.x * blockDim.x) {
        float4 v = ((const float4*)x)[i];
        short4v o;
        o[0] = f2bf(v.x); o[1] = f2bf(v.y); o[2] = f2bf(v.z); o[3] = f2bf(v.w);
        *(short4v*)&w[i * 4] = o;
    }
}

// W [R][C] f32 -> Wt [C][R] bf16
__global__ __launch_bounds__(256) void transpose_w_k(const float* __restrict__ W,
                                                     short* __restrict__ Wt, int R, int C)
{
    __shared__ short t[32][33];
    int c0 = blockIdx.x * 32, r0 = blockIdx.y * 32;
    int tx = threadIdx.x & 31, ty = threadIdx.x >> 5;
#pragma unroll
    for (int i = 0; i < 32; i += 8)
        t[ty + i][tx] = f2bf(W[(long)(r0 + ty + i) * C + c0 + tx]);
    __syncthreads();
#pragma unroll
    for (int i = 0; i < 32; i += 8)
        Wt[(long)(c0 + ty + i) * R + r0 + tx] = t[tx][ty + i];
}

extern "C" void kernel_launch(void* const* d_in, const int* in_sizes, int n_in,
                              void* d_out, int out_size, void* d_ws, size_t ws_size,
                              hipStream_t stream)
{
    const float* x   = (const float*)d_in[0];
    const float* Wq  = (const float*)d_in[1];
    const float* bq  = (const float*)d_in[2];
    const float* Wk  = (const float*)d_in[3];
    const float* bk  = (const float*)d_in[4];
    const float* Wv  = (const float*)d_in[5];
    const float* bv  = (const float*)d_in[6];
    const float* W1  = (const float*)d_in[7];
    const float* b1  = (const float*)d_in[8];
    const float* W2  = (const float*)d_in[9];
    const float* b2  = (const float*)d_in[10];
    const float* g1  = (const float*)d_in[11];
    const float* lb1 = (const float*)d_in[12];
    const float* g2  = (const float*)d_in[13];
    const float* lb2 = (const float*)d_in[14];
    float* out = (float*)d_out;

    char* p = (char*)d_ws;
    auto carve = [&](size_t bytes) -> char* {
        char* r = p;
        p += (bytes + 255) & ~(size_t)255;
        return r;
    };
    short* hbf  = (short*)carve((size_t)WB * WS * WD * 2);
    short* kbf  = (short*)carve((size_t)WB * WS * WD * 2);
    short* vbf  = (short*)carve((size_t)WB * WS * WD * 2);
    short* Gt   = (short*)carve((size_t)WB * WS * WD * 2);   // [b][n][e]
    short* vw1t = (short*)carve((size_t)WB * WHID * WS * 2); // [b][j][s]
    short* wqb  = (short*)carve((size_t)WD * WD * 2);
    short* wkt  = (short*)carve((size_t)WD * WD * 2);
    short* wvt  = (short*)carve((size_t)WD * WD * 2);
    short* w1t  = (short*)carve((size_t)WHID * WD * 2);      // [64][512]
    short* w2t  = (short*)carve((size_t)WD * WHID * 2);      // [512][64]
    float* rq   = (float*)carve((size_t)WB * WS * 4);
    float* Lp   = (float*)carve((size_t)WB * 8 * WS * 4);
    short* Pp   = (short*)carve((size_t)8 * WB * WS * WHID * 2);

    const int M = WB * WS;
    const float sc_attn = 0.125f;
    const float sc_out  = 0.04419417382f;   // 1/sqrt(512)

    conv_x_k<<<2048, 256, 0, stream>>>(x, hbf, WB * WS * WD / 4);
    conv_w_k<<<256, 256, 0, stream>>>(Wq, wqb, WD * WD / 4);
    transpose_w_k<<<dim3(WD / 32, WD / 32), 256, 0, stream>>>(Wk, wkt, WD, WD);
    transpose_w_k<<<dim3(WD / 32, WD / 32), 256, 0, stream>>>(Wv, wvt, WD, WD);
    transpose_w_k<<<dim3(WHID / 32, WD / 32), 256, 0, stream>>>(W1, w1t, WD, WHID);
    transpose_w_k<<<dim3(WD / 32, WHID / 32), 256, 0, stream>>>(W2, w2t, WHID, WD);

    // k = x @ Wk + bk ; v = x @ Wv + bv
    gemm8_k<0><<<dim3(WD / 128, M / 128, 1), 512, 0, stream>>>(
        hbf, wkt, bk, kbf, WD, WD, WD, WD, 0, 0, 0, 1.0f, 0);
    gemm8_k<0><<<dim3(WD / 128, M / 128, 1), 512, 0, stream>>>(
        hbf, wvt, bv, vbf, WD, WD, WD, WD, 0, 0, 0, 1.0f, 0);

    // Gt[b][n][e] = sc_attn * sum_d Wq[e][d]*k[b][n][d]
    gemm8_k<8><<<dim3(WS / 128, WD / 128, WB), 512, 0, stream>>>(
        wqb, kbf, nullptr, Gt, WD, WD, WD, WD,
        0, (long)WS * WD, (long)WS * WD, sc_attn, 0);
    // rq[b][n] = sc_attn * dot(bq, k[b][n])
    rq_k<<<WB * WS / 256, 256, 0, stream>>>(kbf, bq, rq);
    // vw1t[b][j][s] = sum_d W1[d][j]*v[b][s][d]
    gemm_k<<<dim3(WS / 64, 1, WB), 256, 0, stream>>>(
        w1t, vbf, vw1t, WHID, WS, WD, WD, WD, WS,
        0, (long)WS * WD, (long)WHID * WS, 1.0f, 0);

    for (int l = 0; l < NLAYER; l++) {
        qkpv_k<<<dim3(WS / 256, WS / 256, WB), 512, 0, stream>>>(
            hbf, Gt, vw1t, Pp, Lp, rq);
        tail_k<<<M / 32, 512, 0, stream>>>(
            Pp, Lp, b1, w2t, b2, g1, lb1, g2, lb2, hbf,
            (l == NLAYER - 1) ? out : nullptr, sc_out);
    }
}

// Round 19
// 326.464 us; speedup vs baseline: 1.4290x; 1.0217x over previous
//
#include <hip/hip_runtime.h>
#include <hip/hip_bf16.h>
#include <math.h>

#define WB 4
#define WS 2048
#define WD 512
#define WHID 64
#define NLAYER 6

typedef __attribute__((ext_vector_type(8))) short short8;
typedef __attribute__((ext_vector_type(4))) short short4v;
typedef __attribute__((ext_vector_type(4))) float floatx4;
typedef __attribute__((ext_vector_type(16))) float floatx16;

__device__ __forceinline__ short f2bf(float f) {
    union { float f; unsigned u; } x; x.f = f;
    unsigned r = (x.u + 0x7fffu + ((x.u >> 16) & 1u)) >> 16;
    return (short)r;
}

__device__ __forceinline__ float bf2f(short s) {
    union { unsigned u; float f; } c;
    c.u = ((unsigned)(unsigned short)s) << 16;
    return c.f;
}

__device__ __forceinline__ void gl_lds16(const short* g, short* l) {
    __builtin_amdgcn_global_load_lds(
        (const __attribute__((address_space(1))) unsigned*)g,
        (__attribute__((address_space(3))) unsigned*)l, 16, 0, 0);
}

// bijective XCD-aware block swizzle (nwg % 8 == 0)
__device__ __forceinline__ void xcd_swz(int& bx, int& by, int& bz) {
    int gx = gridDim.x, gy = gridDim.y;
    int nwg = gx * gy * gridDim.z;
    int wg = blockIdx.x + gx * (blockIdx.y + gy * blockIdx.z);
    int swz = (wg & 7) * (nwg >> 3) + (wg >> 3);
    bx = swz % gx;
    int t = swz / gx;
    by = t % gy;
    bz = t / gy;
}

// ---------- fused QK'+softmax-exp+PV: 256x256 tile, 32x32x16 MFMA ----------
// Lp row-sums computed in PV phase via ones-column MFMA (8 partials/row).
__global__ __launch_bounds__(512) void qkpv_k(
    const short* __restrict__ A, const short* __restrict__ Bm,
    const short* __restrict__ Vw, short* __restrict__ Pp,
    float* __restrict__ Lp, const float* __restrict__ rq)
{
    __shared__ __align__(16) short As[2][256 * 64];
    __shared__ __align__(16) short Bs[2][256 * 64];
    int bx, by, bz;
    xcd_swz(bx, by, bz);
    int tid = threadIdx.x;
    int m0 = by * 256, n0 = bx * 256;
    const short* Ab = A + (long)bz * WS * WD + (long)m0 * WD;
    const short* Bb = Bm + (long)bz * WS * WD + (long)n0 * WD;

    int lane = tid & 63, w = tid >> 6;
    int l31 = lane & 31, lh = lane >> 5;
    int wm = (w >> 2) * 128, wn = (w & 3) * 64;

    floatx16 acc[4][2];
#pragma unroll
    for (int mi = 0; mi < 4; mi++)
#pragma unroll
        for (int ni = 0; ni < 2; ni++)
#pragma unroll
            for (int r = 0; r < 16; r++) acc[mi][ni][r] = 0.f;

    int sr = tid >> 3;
    int scb = (tid & 7) ^ (sr & 7);
    const short* ga0 = Ab + (long)sr * WD + scb * 8;
    const short* gb0 = Bb + (long)sr * WD + scb * 8;
    long ld64 = (long)64 * WD;

    int aob[4], ax[4], bob[2], bx_[2];
#pragma unroll
    for (int i = 0; i < 4; i++) {
        int ar = wm + i * 32 + l31;
        aob[i] = ar * 64; ax[i] = ar & 7;
    }
#pragma unroll
    for (int i = 0; i < 2; i++) {
        int br = wn + i * 32 + l31;
        bob[i] = br * 64; bx_[i] = br & 7;
    }

    auto stage = [&](int t, int b) {
        const short* ga = ga0 + t * 64;
        const short* gb = gb0 + t * 64;
#pragma unroll
        for (int q = 0; q < 4; q++)
            gl_lds16(ga + (long)q * ld64, &As[b][q * 4096 + tid * 8]);
#pragma unroll
        for (int q = 0; q < 4; q++)
            gl_lds16(gb + (long)q * ld64, &Bs[b][q * 4096 + tid * 8]);
    };

    stage(0, 0);

    const int nt = WD >> 6;
    for (int t = 0; t < nt; t++) {
        int cur = t & 1;
        if (t + 1 < nt) {
            stage(t + 1, cur ^ 1);
            asm volatile("s_waitcnt vmcnt(8)" ::: "memory");
        } else {
            asm volatile("s_waitcnt vmcnt(0)" ::: "memory");
        }
        __builtin_amdgcn_s_barrier();
        __builtin_amdgcn_sched_barrier(0);
        const short* as = As[cur];
        const short* bs = Bs[cur];
#pragma unroll
        for (int kk = 0; kk < 4; kk++) {
            short8 av[4], bv[2];
#pragma unroll
            for (int i = 0; i < 4; i++)
                av[i] = *(const short8*)&as[aob[i] + (((2 * kk + lh) ^ ax[i]) * 8)];
#pragma unroll
            for (int i = 0; i < 2; i++)
                bv[i] = *(const short8*)&bs[bob[i] + (((2 * kk + lh) ^ bx_[i]) * 8)];
#pragma unroll
            for (int mi = 0; mi < 4; mi++)
#pragma unroll
                for (int ni = 0; ni < 2; ni++)
                    acc[mi][ni] = __builtin_amdgcn_mfma_f32_32x32x16_bf16(av[mi], bv[ni], acc[mi][ni], 0, 0, 0);
        }
        __builtin_amdgcn_sched_barrier(0);
        __builtin_amdgcn_s_barrier();
    }

    // exp -> P into LDS (swizzled halves); no in-epilogue row sums
    short* Pl = (short*)As;
    short* Ph = (short*)Bs;
    float rv0 = rq[(long)bz * WS + n0 + wn + l31];
    float rv1 = rq[(long)bz * WS + n0 + wn + 32 + l31];
#pragma unroll
    for (int mi = 0; mi < 4; mi++) {
#pragma unroll
        for (int ni = 0; ni < 2; ni++) {
            int c = wn + ni * 32 + l31;
            short* Pt = (c < 128) ? Pl : Ph;
            int cc = c & 127;
            float rv = ni ? rv1 : rv0;
#pragma unroll
            for (int r = 0; r < 16; r++) {
                int row = wm + mi * 32 + 4 * lh + (r & 3) + 8 * (r >> 2);
                float e = __expf(acc[mi][ni][r] + rv);
                int blk = (cc >> 3) ^ (row & 7);
                Pt[row * 128 + blk * 8 + (cc & 7)] = f2bf(e);
            }
        }
    }
    __syncthreads();

    // PV: wave w computes rows w*32..+31 x 64 j, K=256 from LDS P; ones-col -> Lp
    {
        int m0w = w * 32;
        int l15 = lane & 15, kb = lane >> 4;
        floatx4 acc2[2][4];
        floatx4 accl[2];
#pragma unroll
        for (int mi = 0; mi < 2; mi++) {
#pragma unroll
            for (int ni = 0; ni < 4; ni++) acc2[mi][ni] = (floatx4){0.f, 0.f, 0.f, 0.f};
            accl[mi] = (floatx4){0.f, 0.f, 0.f, 0.f};
        }
        short8 ones8;
#pragma unroll
        for (int e = 0; e < 8; e++) ones8[e] = (short)0x3F80;  // bf16 1.0
        const short* vb = Vw + (long)bz * WHID * WS + n0;
#pragma unroll
        for (int ks = 0; ks < 8; ks++) {
            int kc = ks * 32 + kb * 8;
            const short* Pt = (kc < 128) ? Pl : Ph;
            int cc = kc & 127;
            short8 av2[2], bv2[4];
#pragma unroll
            for (int mi = 0; mi < 2; mi++) {
                int row = m0w + mi * 16 + l15;
                int blk = (cc >> 3) ^ (row & 7);
                av2[mi] = *(const short8*)&Pt[row * 128 + blk * 8];
            }
#pragma unroll
            for (int ni = 0; ni < 4; ni++) {
                int j = ni * 16 + l15;
                bv2[ni] = *(const short8*)&vb[(long)j * WS + kc];
            }
#pragma unroll
            for (int mi = 0; mi < 2; mi++) {
#pragma unroll
                for (int ni = 0; ni < 4; ni++)
                    acc2[mi][ni] = __builtin_amdgcn_mfma_f32_16x16x32_bf16(av2[mi], bv2[ni], acc2[mi][ni], 0, 0, 0);
                accl[mi] = __builtin_amdgcn_mfma_f32_16x16x32_bf16(av2[mi], ones8, accl[mi], 0, 0, 0);
            }
        }
        int rl = kb * 4;
        short* pp = Pp + (((long)bx * WB + bz) * WS + m0 + m0w) * WHID;
#pragma unroll
        for (int mi = 0; mi < 2; mi++)
#pragma unroll
            for (int ni = 0; ni < 4; ni++) {
                int j = ni * 16 + l15;
#pragma unroll
                for (int q = 0; q < 4; q++)
                    pp[(long)(mi * 16 + rl + q) * WHID + j] = f2bf(acc2[mi][ni][q]);
            }
        if (l15 == 0) {
            float* lp = Lp + ((long)bz * 8 + bx) * WS + m0 + m0w;
#pragma unroll
            for (int mi = 0; mi < 2; mi++)
#pragma unroll
                for (int q = 0; q < 4; q++)
                    lp[mi * 16 + rl + q] = accl[mi][q];
        }
    }
}

// ---------- fused tail: Pp-reduce(8) + relu + FFN2 + residual + LN1 + LN2 ----------
__global__ __launch_bounds__(512) void tail_k(
    const short* __restrict__ Pp, const float* __restrict__ Lp,
    const float* __restrict__ b1, const short* __restrict__ w2t,
    const float* __restrict__ b2,
    const float* __restrict__ g1, const float* __restrict__ bb1,
    const float* __restrict__ g2, const float* __restrict__ bb2,
    short* __restrict__ hbf, float* __restrict__ outp, float sc)
{
    __shared__ __align__(16) short hids[32 * 64];
    __shared__ float ffs[32 * 521];
    int tid = threadIdx.x;
    int lane = tid & 63, w = tid >> 6;
    int row0 = blockIdx.x * 32;

    // step 1: hid = relu(sc/l * sum_bxp Pp + b1) -> hids (bf16, swizzled)
    {
        int r = tid >> 4, l16 = tid & 15;
        int m = row0 + r;
        int b = m >> 11, mm = m & (WS - 1);
        const float* lp = Lp + (long)b * 8 * WS + mm;
        float lv = 0.f;
#pragma unroll
        for (int p2 = 0; p2 < 8; p2++) lv += lp[(long)p2 * WS];
        float scl = sc / lv;
        int j0 = l16 * 4;
        float4 s4 = make_float4(0.f, 0.f, 0.f, 0.f);
#pragma unroll
        for (int bxp = 0; bxp < 8; bxp++) {
            short4v v = *(const short4v*)&Pp[(((long)bxp * WB + b) * WS + mm) * WHID + j0];
            s4.x += bf2f(v[0]); s4.y += bf2f(v[1]); s4.z += bf2f(v[2]); s4.w += bf2f(v[3]);
        }
        short4v hv;
        hv[0] = f2bf(fmaxf(s4.x * scl + b1[j0], 0.f));
        hv[1] = f2bf(fmaxf(s4.y * scl + b1[j0 + 1], 0.f));
        hv[2] = f2bf(fmaxf(s4.z * scl + b1[j0 + 2], 0.f));
        hv[3] = f2bf(fmaxf(s4.w * scl + b1[j0 + 3], 0.f));
        *(short4v*)&hids[r * 64 + (((j0 >> 3) ^ (r & 7)) * 8) + (j0 & 7)] = hv;
    }
    __syncthreads();

    // step 2: ff = hid @ W2 : 8 waves 2Mx4N, wave 16x128, K=64; W2 frags from global
    {
        int wm = (w >> 2) * 16, wn = (w & 3) * 128;
        int l15 = lane & 15, kb = lane >> 4;
        floatx4 acc[8];
#pragma unroll
        for (int ni = 0; ni < 8; ni++) acc[ni] = (floatx4){0.f, 0.f, 0.f, 0.f};
#pragma unroll
        for (int st = 0; st < 2; st++) {
            int jb = st * 4 + kb;
            int ar = wm + l15;
            short8 a = *(const short8*)&hids[ar * 64 + ((jb ^ (ar & 7)) * 8)];
#pragma unroll
            for (int ni = 0; ni < 8; ni++) {
                int n = wn + ni * 16 + l15;
                short8 bf = *(const short8*)&w2t[n * 64 + jb * 8];
                acc[ni] = __builtin_amdgcn_mfma_f32_16x16x32_bf16(a, bf, acc[ni], 0, 0, 0);
            }
        }
#pragma unroll
        for (int ni = 0; ni < 8; ni++) {
            int n = wn + ni * 16 + l15;
            float bvv = b2[n];
#pragma unroll
            for (int q = 0; q < 4; q++) {
                int rr = wm + kb * 4 + q;
                ffs[rr * 521 + n] = acc[ni][q] + bvv;
            }
        }
    }
    __syncthreads();

    // LN1+LN2 per row; wave handles rows w*4..+3
    for (int rr = w * 4; rr < w * 4 + 4; rr++) {
        long m2 = row0 + rr;
        float v[8];
        float s = 0.f;
#pragma unroll
        for (int cc = 0; cc < 8; cc++) {
            int col = lane + 64 * cc;
            float fv = ffs[rr * 521 + col];
            float hv2 = bf2f(hbf[m2 * WD + col]);
            v[cc] = fv + hv2;
            s += v[cc];
        }
#pragma unroll
        for (int off = 1; off < 64; off <<= 1) s += __shfl_xor(s, off);
        float mu = s * (1.f / WD);
        float var = 0.f;
#pragma unroll
        for (int cc = 0; cc < 8; cc++) { v[cc] -= mu; var += v[cc] * v[cc]; }
#pragma unroll
        for (int off = 1; off < 64; off <<= 1) var += __shfl_xor(var, off);
        float rs = rsqrtf(var * (1.f / WD) + 1e-5f);
        float s2 = 0.f;
#pragma unroll
        for (int cc = 0; cc < 8; cc++) {
            int col = lane + 64 * cc;
            v[cc] = v[cc] * rs * g1[col] + bb1[col];
            s2 += v[cc];
        }
#pragma unroll
        for (int off = 1; off < 64; off <<= 1) s2 += __shfl_xor(s2, off);
        float mu2 = s2 * (1.f / WD);
        float var2 = 0.f;
#pragma unroll
        for (int cc = 0; cc < 8; cc++) { v[cc] -= mu2; var2 += v[cc] * v[cc]; }
#pragma unroll
        for (int off = 1; off < 64; off <<= 1) var2 += __shfl_xor(var2, off);
        float rs2 = rsqrtf(var2 * (1.f / WD) + 1e-5f);
#pragma unroll
        for (int cc = 0; cc < 8; cc++) {
            int col = lane + 64 * cc;
            float z = v[cc] * rs2 * g2[col] + bb2[col];
            hbf[m2 * WD + col] = f2bf(z);
            if (outp) outp[m2 * WD + col] = z;
        }
    }
}

// ---------- 128x128 NT GEMM, 8 waves, BK=64, 2-buf counted-vmcnt ----------
template<int EPI>
__global__ __launch_bounds__(512) void gemm8_k(
    const short* __restrict__ A, const short* __restrict__ Bm,
    const float* __restrict__ bias, short* __restrict__ Cb,
    int K, int lda, int ldb, int ldc,
    long sA, long sB, long sC, float scale, int b0)
{
    __shared__ __align__(16) short As[2][128 * 64];
    __shared__ __align__(16) short Bs[2][128 * 64];
    int bx, by, bz0;
    xcd_swz(bx, by, bz0);
    int tid = threadIdx.x;
    int bz = b0 + bz0;
    int m0 = by * 128, n0 = bx * 128;
    const short* Ab = A + (long)bz * sA + (long)m0 * lda;
    const short* Bb = Bm + (long)bz * sB + (long)n0 * ldb;
    long coff = (long)bz * sC;

    int lane = tid & 63, w = tid >> 6;
    int wm = (w >> 2) * 64, wn = (w & 3) * 32;

    floatx4 acc[4][2];
#pragma unroll
    for (int mi = 0; mi < 4; mi++)
#pragma unroll
        for (int ni = 0; ni < 2; ni++) acc[mi][ni] = (floatx4){0.f, 0.f, 0.f, 0.f};

    int r0 = tid >> 3;
    int sblk = (tid & 7) ^ (r0 & 7);
    const short* ga0 = Ab + (long)r0 * lda + sblk * 8;
    const short* gb0 = Bb + (long)r0 * ldb + sblk * 8;
    long lda64 = (long)64 * lda, ldb64 = (long)64 * ldb;

    int arow = wm + (lane & 15);
    int brow = wn + (lane & 15);
    int a7 = arow & 7, b7 = brow & 7;
    int kb = lane >> 4;
    int aoff0 = arow * 64 + ((kb ^ a7) * 8);
    int aoff1 = arow * 64 + (((kb + 4) ^ a7) * 8);
    int boff0 = brow * 64 + ((kb ^ b7) * 8);
    int boff1 = brow * 64 + (((kb + 4) ^ b7) * 8);

    int nt = K >> 6;

    auto stage = [&](int t, int b) {
        const short* ga = ga0 + t * 64;
        const short* gb = gb0 + t * 64;
        gl_lds16(ga, &As[b][tid * 8]);
        gl_lds16(ga + lda64, &As[b][(tid + 512) * 8]);
        gl_lds16(gb, &Bs[b][tid * 8]);
        gl_lds16(gb + ldb64, &Bs[b][(tid + 512) * 8]);
    };

    stage(0, 0);

    for (int t = 0; t < nt; t++) {
        int cur = t & 1;
        if (t + 1 < nt) {
            stage(t + 1, cur ^ 1);
            asm volatile("s_waitcnt vmcnt(4)" ::: "memory");
        } else {
            asm volatile("s_waitcnt vmcnt(0)" ::: "memory");
        }
        __builtin_amdgcn_s_barrier();
        __builtin_amdgcn_sched_barrier(0);
        const short* as = As[cur];
        const short* bs = Bs[cur];
        short8 av[4], bv[2];
#pragma unroll
        for (int i = 0; i < 4; i++) av[i] = *(const short8*)&as[aoff0 + i * 16 * 64];
#pragma unroll
        for (int i = 0; i < 2; i++) bv[i] = *(const short8*)&bs[boff0 + i * 16 * 64];
#pragma unroll
        for (int mi = 0; mi < 4; mi++)
#pragma unroll
            for (int ni = 0; ni < 2; ni++)
                acc[mi][ni] = __builtin_amdgcn_mfma_f32_16x16x32_bf16(av[mi], bv[ni], acc[mi][ni], 0, 0, 0);
#pragma unroll
        for (int i = 0; i < 4; i++) av[i] = *(const short8*)&as[aoff1 + i * 16 * 64];
#pragma unroll
        for (int i = 0; i < 2; i++) bv[i] = *(const short8*)&bs[boff1 + i * 16 * 64];
#pragma unroll
        for (int mi = 0; mi < 4; mi++)
#pragma unroll
            for (int ni = 0; ni < 2; ni++)
                acc[mi][ni] = __builtin_amdgcn_mfma_f32_16x16x32_bf16(av[mi], bv[ni], acc[mi][ni], 0, 0, 0);
        __builtin_amdgcn_sched_barrier(0);
        __builtin_amdgcn_s_barrier();
    }

    int rl = (lane >> 4) * 4, col = lane & 15;

#pragma unroll
    for (int mi = 0; mi < 4; mi++) {
#pragma unroll
        for (int ni = 0; ni < 2; ni++) {
            int n = n0 + wn + ni * 16 + col;
            if (EPI == 8) {
                int m = m0 + wm + mi * 16 + rl;
                short4v o;
#pragma unroll
                for (int j = 0; j < 4; j++) o[j] = f2bf(acc[mi][ni][j] * scale);
                *(short4v*)&Cb[coff + (long)n * ldc + m] = o;
            } else {
                float bvv = bias ? bias[n] : 0.f;
#pragma unroll
                for (int j = 0; j < 4; j++) {
                    int r = wm + mi * 16 + rl + j;
                    float v = (acc[mi][ni][j] + bvv) * scale;
                    Cb[coff + (long)(m0 + r) * ldc + n] = f2bf(v);
                }
            }
        }
    }
}

// rq[b][n] = sc_attn * dot(bq, k[b][n]); k rows stride ldk
__global__ __launch_bounds__(256) void rq_k(const short* __restrict__ kbf,
                                            const float* __restrict__ bq,
                                            float* __restrict__ rq, int ldk)
{
    __shared__ float sbq[WD];
    int tid = threadIdx.x;
    for (int i = tid; i < WD; i += 256) sbq[i] = bq[i];
    __syncthreads();
    int idx = blockIdx.x * 256 + tid;
    const short* kr = kbf + (long)idx * ldk;
    float s = 0.f;
    for (int d = 0; d < WD; d += 8) {
        short8 kv = *(const short8*)(kr + d);
#pragma unroll
        for (int e = 0; e < 8; e++) s += bf2f(kv[e]) * sbq[d + e];
    }
    rq[idx] = s * 0.125f;
}

// ---------------- 64-tile GEMM (M<=64): C = A@B^T * scale, bf16 out ----------------
__global__ __launch_bounds__(256) void gemm_k(
    const short* __restrict__ A, const short* __restrict__ Bm,
    short* __restrict__ Cb,
    int M, int N, int K, int lda, int ldb, int ldc,
    long sA, long sB, long sC, float scale, int b0)
{
    __shared__ short As[64][40];
    __shared__ short Bs[64][40];
    int bx, by, bz0;
    xcd_swz(bx, by, bz0);
    int tid = threadIdx.x;
    int bz = b0 + bz0;
    const short* Ab = A + (long)bz * sA;
    const short* Bb = Bm + (long)bz * sB;
    long coff = (long)bz * sC;
    int m0 = by * 64, n0 = bx * 64;

    floatx4 acc[4];
#pragma unroll
    for (int c = 0; c < 4; c++) acc[c] = (floatx4){0.f, 0.f, 0.f, 0.f};

    int lane = tid & 63, w = tid >> 6;
    int arow = w * 16 + (lane & 15);
    int koff = (lane >> 4) * 8;

    for (int kt = 0; kt < K; kt += 32) {
        {
            int r = tid >> 2, kc = (tid & 3) * 8;
            int ar = m0 + r < M ? m0 + r : M - 1;
            short8 av = *(const short8*)(Ab + (long)ar * lda + kt + kc);
            *(short8*)&As[r][kc] = av;
        }
        {
            int r = tid >> 2, kc = (tid & 3) * 8;
            short8 bv = *(const short8*)(Bb + (long)(n0 + r) * ldb + kt + kc);
            *(short8*)&Bs[r][kc] = bv;
        }
        __syncthreads();
        short8 a = *(const short8*)&As[arow][koff];
#pragma unroll
        for (int c = 0; c < 4; c++) {
            short8 b = *(const short8*)&Bs[c * 16 + (lane & 15)][koff];
            acc[c] = __builtin_amdgcn_mfma_f32_16x16x32_bf16(a, b, acc[c], 0, 0, 0);
        }
        __syncthreads();
    }

    int rl = (lane >> 4) * 4, col = lane & 15;
    int mb = m0 + w * 16 + rl;
#pragma unroll
    for (int c = 0; c < 4; c++) {
        int n = n0 + c * 16 + col;
#pragma unroll
        for (int j = 0; j < 4; j++) {
            int m = mb + j;
            if (m < M) Cb[coff + (long)m * ldc + n] = f2bf(acc[c][j] * scale);
        }
    }
}

__global__ void conv_x_k(const float* __restrict__ x, short* __restrict__ hbf, int n4)
{
    int i = blockIdx.x * blockDim.x + threadIdx.x;
    for (; i < n4; i += gridDim.x * blockDim.x) {
        float4 v = ((const float4*)x)[i];
        short4v o;
        o[0] = f2bf(v.x); o[1] = f2bf(v.y); o[2] = f2bf(v.z); o[3] = f2bf(v.w);
        *(short4v*)&hbf[i * 4] = o;
    }
}

__global__ void conv_w_k(const float* __restrict__ x, short* __restrict__ w, int n4)
{
    int i = blockIdx.x * blockDim.x + threadIdx.x;
    for (; i < n4; i += gridDim.x * blockDim.x) {
        float4 v = ((const float4*)x)[i];
        short4v o;
        o[0] = f2bf(v.x); o[1] = f2bf(v.y); o[2] = f2bf(v.z); o[3] = f2bf(v.w);
        *(short4v*)&w[i * 4] = o;
    }
}

// concat bias: bkv[0..511]=bk, bkv[512..1023]=bv
__global__ void cat_bias_k(const float* __restrict__ bk, const float* __restrict__ bv,
                           float* __restrict__ bkv)
{
    int i = threadIdx.x + blockIdx.x * 256;
    if (i < WD) bkv[i] = bk[i];
    else bkv[i] = bv[i - WD];
}

// W [R][C] f32 -> Wt [C][R] bf16
__global__ __launch_bounds__(256) void transpose_w_k(const float* __restrict__ W,
                                                     short* __restrict__ Wt, int R, int C)
{
    __shared__ short t[32][33];
    int c0 = blockIdx.x * 32, r0 = blockIdx.y * 32;
    int tx = threadIdx.x & 31, ty = threadIdx.x >> 5;
#pragma unroll
    for (int i = 0; i < 32; i += 8)
        t[ty + i][tx] = f2bf(W[(long)(r0 + ty + i) * C + c0 + tx]);
    __syncthreads();
#pragma unroll
    for (int i = 0; i < 32; i += 8)
        Wt[(long)(c0 + ty + i) * R + r0 + tx] = t[tx][ty + i];
}

extern "C" void kernel_launch(void* const* d_in, const int* in_sizes, int n_in,
                              void* d_out, int out_size, void* d_ws, size_t ws_size,
                              hipStream_t stream)
{
    const float* x   = (const float*)d_in[0];
    const float* Wq  = (const float*)d_in[1];
    const float* bq  = (const float*)d_in[2];
    const float* Wk  = (const float*)d_in[3];
    const float* bk  = (const float*)d_in[4];
    const float* Wv  = (const float*)d_in[5];
    const float* bv  = (const float*)d_in[6];
    const float* W1  = (const float*)d_in[7];
    const float* b1  = (const float*)d_in[8];
    const float* W2  = (const float*)d_in[9];
    const float* b2  = (const float*)d_in[10];
    const float* g1  = (const float*)d_in[11];
    const float* lb1 = (const float*)d_in[12];
    const float* g2  = (const float*)d_in[13];
    const float* lb2 = (const float*)d_in[14];
    float* out = (float*)d_out;

    char* p = (char*)d_ws;
    auto carve = [&](size_t bytes) -> char* {
        char* r = p;
        p += (bytes + 255) & ~(size_t)255;
        return r;
    };
    short* hbf  = (short*)carve((size_t)WB * WS * WD * 2);
    short* kvbf = (short*)carve((size_t)WB * WS * 1024 * 2);  // [b][s][K(512)|V(512)]
    short* Gt   = (short*)carve((size_t)WB * WS * WD * 2);    // [b][n][d]
    short* vw1t = (short*)carve((size_t)WB * WHID * WS * 2);  // [b][j][s]
    short* wqb  = (short*)carve((size_t)WD * WD * 2);
    short* wkvt = (short*)carve((size_t)1024 * WD * 2);       // [Wk^T ; Wv^T]
    short* w1t  = (short*)carve((size_t)WHID * WD * 2);       // [64][512]
    short* w2t  = (short*)carve((size_t)WD * WHID * 2);       // [512][64]
    float* bkv  = (float*)carve((size_t)1024 * 4);
    float* rq   = (float*)carve((size_t)WB * WS * 4);
    float* Lp   = (float*)carve((size_t)WB * 8 * WS * 4);
    short* Pp   = (short*)carve((size_t)8 * WB * WS * WHID * 2);

    const int M = WB * WS;
    const float sc_attn = 0.125f;
    const float sc_out  = 0.04419417382f;   // 1/sqrt(512)

    conv_x_k<<<2048, 256, 0, stream>>>(x, hbf, WB * WS * WD / 4);
    conv_w_k<<<256, 256, 0, stream>>>(Wq, wqb, WD * WD / 4);
    transpose_w_k<<<dim3(WD / 32, WD / 32), 256, 0, stream>>>(Wk, wkvt, WD, WD);
    transpose_w_k<<<dim3(WD / 32, WD / 32), 256, 0, stream>>>(Wv, wkvt + (size_t)WD * WD, WD, WD);
    transpose_w_k<<<dim3(WHID / 32, WD / 32), 256, 0, stream>>>(W1, w1t, WD, WHID);
    transpose_w_k<<<dim3(WD / 32, WHID / 32), 256, 0, stream>>>(W2, w2t, WHID, WD);
    cat_bias_k<<<4, 256, 0, stream>>>(bk, bv, bkv);

    // [k|v] = x @ [Wk|Wv] + [bk|bv]   (one N=1024 GEMM)
    gemm8_k<0><<<dim3(1024 / 128, M / 128, 1), 512, 0, stream>>>(
        hbf, wkvt, bkv, kvbf, WD, WD, WD, 1024, 0, 0, 0, 1.0f, 0);
    const short* kbf = kvbf;            // ld 1024
    const short* vbf = kvbf + WD;       // ld 1024

    // Gt[b][n][d] = sc_attn * sum_e Wq[d][e]*k[b][n][e]
    gemm8_k<8><<<dim3(WS / 128, WD / 128, WB), 512, 0, stream>>>(
        wqb, kbf, nullptr, Gt, WD, WD, 1024, WD,
        0, (long)WS * 1024, (long)WS * WD, sc_attn, 0);
    // rq[b][n] = sc_attn * dot(bq, k[b][n])
    rq_k<<<WB * WS / 256, 256, 0, stream>>>(kbf, bq, rq, 1024);
    // vw1t[b][j][s] = sum_d W1[d][j]*v[b][s][d]
    gemm_k<<<dim3(WS / 64, 1, WB), 256, 0, stream>>>(
        w1t, vbf, vw1t, WHID, WS, WD, WD, 1024, WS,
        0, (long)WS * 1024, (long)WHID * WS, 1.0f, 0);

    for (int l = 0; l < NLAYER; l++) {
        qkpv_k<<<dim3(WS / 256, WS / 256, WB), 512, 0, stream>>>(
            hbf, Gt, vw1t, Pp, Lp, rq);
        tail_k<<<M / 32, 512, 0, stream>>>(
            Pp, Lp, b1, w2t, b2, g1, lb1, g2, lb2, hbf,
            (l == NLAYER - 1) ? out : nullptr, sc_out);
    }
}